// Round 2
// baseline (1052.332 us; speedup 1.0000x reference)
//
#include <hip/hip_runtime.h>
#include <math.h>

#define H 512
#define V 50257
#define B 32
#define L 50

typedef float f4 __attribute__((ext_vector_type(4)));

__device__ __forceinline__ float sigmoidf_(float x) { return 1.f / (1.f + expf(-x)); }

__device__ __forceinline__ float dot4(f4 a, f4 b) {
    return a.x * b.x + a.y * b.y + a.z * b.z + a.w * b.w;
}

// ---------------------------------------------------------------------------
// K1: attention energies + softmax + context + embedding gather
// grid: 32 blocks (one per batch) x 256 threads
// ---------------------------------------------------------------------------
__global__ __launch_bounds__(256) void k1_attn(const int* __restrict__ input_data,
                                               const float* __restrict__ h0,
                                               const float* __restrict__ enc,
                                               const float* __restrict__ emb,
                                               float* __restrict__ attn_out,
                                               float* __restrict__ rnn_in,
                                               float* __restrict__ ctx) {
    int b = blockIdx.x;
    int tid = threadIdx.x;
    int lane = tid & 63, w = tid >> 6;
    __shared__ float sm[64];

    // energies[b][l] = <h0[b,:], enc[l,b,:]>
    for (int l = w; l < L; l += 4) {
        const f4* e4 = (const f4*)(enc + (size_t)(l * B + b) * H);
        const f4* h4 = (const f4*)(h0 + (size_t)b * H);
        float s = 0.f;
#pragma unroll
        for (int i = 0; i < 2; ++i) {
            s += dot4(e4[lane + 64 * i], h4[lane + 64 * i]);
        }
        for (int off = 32; off; off >>= 1) s += __shfl_down(s, off, 64);
        if (lane == 0) sm[l] = s;
    }
    __syncthreads();

    // softmax over l (wave 0)
    if (w == 0) {
        float e = (lane < L) ? sm[lane] : -INFINITY;
        float m = e;
        for (int off = 32; off; off >>= 1) m = fmaxf(m, __shfl_xor(m, off, 64));
        float p = (lane < L) ? expf(e - m) : 0.f;
        float s = p;
        for (int off = 32; off; off >>= 1) s += __shfl_xor(s, off, 64);
        float a = p / s;
        if (lane < L) {
            sm[lane] = a;
            attn_out[b * L + lane] = a;
        }
    }
    __syncthreads();

    // context[b][h] = sum_l attn[l] * enc[l,b,h]; rnn_in = [embedded | context]
    int idx = input_data[b];
    for (int h = tid; h < H; h += 256) {
        float c = 0.f;
#pragma unroll 5
        for (int l = 0; l < L; ++l) c += sm[l] * enc[(size_t)(l * B + b) * H + h];
        ctx[b * H + h] = c;
        rnn_in[b * 1024 + 512 + h] = c;
        rnn_in[b * 1024 + h] = emb[(size_t)idx * H + h];
    }
}

// ---------------------------------------------------------------------------
// K2: gates[b][n] = rnn_in[b,:] @ W_ih[n,:] + h0[b,:] @ W_hh[n,:] + b_ih + b_hh
// grid: 32 blocks x 256 threads; 64 gate-rows per block, deep k-unroll (16)
// thread tile: 2 rows x 4 batches
// ---------------------------------------------------------------------------
__global__ __launch_bounds__(256) void k2_gates(const float* __restrict__ rnn_in,
                                                const float* __restrict__ h0,
                                                const float* __restrict__ W_ih,
                                                const float* __restrict__ W_hh,
                                                const float* __restrict__ b_ih,
                                                const float* __restrict__ b_hh,
                                                float* __restrict__ gates) {
    int t = threadIdx.x;
    int tn = t & 31, tb = t >> 5;
    int n0 = blockIdx.x * 64 + tn * 2;   // 2 rows
    int b0 = tb * 4;                      // 4 batches
    float acc[4][2] = {};                 // [batch][row]

    // W_ih part (K = 1024)
    for (int k = 0; k < 1024; k += 16) {
        f4 wv[2][4], xv[4][4];
#pragma unroll
        for (int j = 0; j < 2; ++j)
#pragma unroll
            for (int u = 0; u < 4; ++u)
                wv[j][u] = __builtin_nontemporal_load(
                    (const f4*)(W_ih + (size_t)(n0 + j) * 1024 + k + u * 4));
#pragma unroll
        for (int i = 0; i < 4; ++i)
#pragma unroll
            for (int u = 0; u < 4; ++u)
                xv[i][u] = *(const f4*)(rnn_in + (b0 + i) * 1024 + k + u * 4);
#pragma unroll
        for (int i = 0; i < 4; ++i)
#pragma unroll
            for (int j = 0; j < 2; ++j)
#pragma unroll
                for (int u = 0; u < 4; ++u)
                    acc[i][j] += dot4(xv[i][u], wv[j][u]);
    }
    // W_hh part (K = 512)
    for (int k = 0; k < 512; k += 16) {
        f4 wv[2][4], xv[4][4];
#pragma unroll
        for (int j = 0; j < 2; ++j)
#pragma unroll
            for (int u = 0; u < 4; ++u)
                wv[j][u] = __builtin_nontemporal_load(
                    (const f4*)(W_hh + (size_t)(n0 + j) * 512 + k + u * 4));
#pragma unroll
        for (int i = 0; i < 4; ++i)
#pragma unroll
            for (int u = 0; u < 4; ++u)
                xv[i][u] = *(const f4*)(h0 + (b0 + i) * 512 + k + u * 4);
#pragma unroll
        for (int i = 0; i < 4; ++i)
#pragma unroll
            for (int j = 0; j < 2; ++j)
#pragma unroll
                for (int u = 0; u < 4; ++u)
                    acc[i][j] += dot4(xv[i][u], wv[j][u]);
    }
#pragma unroll
    for (int i = 0; i < 4; ++i)
#pragma unroll
        for (int j = 0; j < 2; ++j)
            gates[(b0 + i) * 2048 + n0 + j] =
                acc[i][j] + b_ih[n0 + j] + b_hh[n0 + j];
}

// ---------------------------------------------------------------------------
// K3: LSTM pointwise; writes h1, c1 outputs and xout = [h1 | context]
// ---------------------------------------------------------------------------
__global__ __launch_bounds__(256) void k3_lstm(const float* __restrict__ gates,
                                               const float* __restrict__ c0,
                                               const float* __restrict__ ctx,
                                               float* __restrict__ h1_out,
                                               float* __restrict__ c1_out,
                                               float* __restrict__ xout) {
    int id = blockIdx.x * 256 + threadIdx.x;
    if (id >= B * H) return;
    int b = id >> 9, h = id & 511;
    const float* g = gates + b * 2048;
    float ig = g[h];
    float fg = g[512 + h];
    float gg = g[1024 + h];
    float og = g[1536 + h];
    float c = sigmoidf_(fg) * c0[id] + sigmoidf_(ig) * tanhf(gg);
    float hh = sigmoidf_(og) * tanhf(c);
    c1_out[id] = c;
    h1_out[id] = hh;
    xout[b * 1024 + h] = hh;
    xout[b * 1024 + 512 + h] = ctx[id];
}

// ---------------------------------------------------------------------------
// K4: logits[b][n] = xout[b,:] @ W_out[n,:] + b_out[n]
// grid: 393 blocks x 256 threads; 128 rows/block; thread tile 4 rows x 4
// batches; k-unroll 16 for MLP; nontemporal W loads (keep xout in L2).
// ---------------------------------------------------------------------------
__global__ __launch_bounds__(256) void k4_logits(const float* __restrict__ xout,
                                                 const float* __restrict__ W_out,
                                                 const float* __restrict__ b_out,
                                                 float* __restrict__ logits) {
    int t = threadIdx.x;
    int tn = t & 31, tb = t >> 5;
    int n0 = blockIdx.x * 128 + tn * 4;
    int b0 = tb * 4;

    if (n0 + 3 < V) {
        float acc[4][4] = {};  // [batch][row]
        const float* wp0 = W_out + (size_t)n0 * 1024;
        for (int k = 0; k < 1024; k += 16) {
            f4 wv[4][4], xv[4][4];
#pragma unroll
            for (int j = 0; j < 4; ++j)
#pragma unroll
                for (int u = 0; u < 4; ++u)
                    wv[j][u] = __builtin_nontemporal_load(
                        (const f4*)(wp0 + (size_t)j * 1024 + k + u * 4));
#pragma unroll
            for (int i = 0; i < 4; ++i)
#pragma unroll
                for (int u = 0; u < 4; ++u)
                    xv[i][u] = *(const f4*)(xout + (b0 + i) * 1024 + k + u * 4);
#pragma unroll
            for (int i = 0; i < 4; ++i)
#pragma unroll
                for (int j = 0; j < 4; ++j)
#pragma unroll
                    for (int u = 0; u < 4; ++u)
                        acc[i][j] += dot4(xv[i][u], wv[j][u]);
        }
#pragma unroll
        for (int i = 0; i < 4; ++i)
#pragma unroll
            for (int j = 0; j < 4; ++j)
                logits[(size_t)(b0 + i) * V + n0 + j] = acc[i][j] + b_out[n0 + j];
    } else {
        // tail block: per-row guarded (1 block only)
        for (int j = 0; j < 4; ++j) {
            if (n0 + j >= V) continue;
            float a[4] = {0.f, 0.f, 0.f, 0.f};
            for (int k = 0; k < 1024; k += 4) {
                f4 wv = *(const f4*)(W_out + (size_t)(n0 + j) * 1024 + k);
#pragma unroll
                for (int i = 0; i < 4; ++i) {
                    f4 xv = *(const f4*)(xout + (b0 + i) * 1024 + k);
                    a[i] += dot4(xv, wv);
                }
            }
#pragma unroll
            for (int i = 0; i < 4; ++i)
                logits[(size_t)(b0 + i) * V + n0 + j] = a[i] + b_out[n0 + j];
        }
    }
}

// ---------------------------------------------------------------------------
// K5a: per-(row, slice) online (max, sumexp) partials. grid 32*8 blocks.
// ---------------------------------------------------------------------------
#define SLICE 6283  // ceil(V/8)

__global__ __launch_bounds__(256) void k5a_partial(const float* __restrict__ logits,
                                                   float* __restrict__ part) {
    int b = blockIdx.x >> 3, s = blockIdx.x & 7;
    int tid = threadIdx.x;
    int lane = tid & 63, w = tid >> 6;
    int start = s * SLICE;
    int end = min(start + SLICE, V);

    float m = -INFINITY, sum = 0.f;
    for (int v = start + tid; v < end; v += 256) {
        float x = logits[(size_t)b * V + v];
        if (x > m) {
            sum = sum * expf(m - x) + 1.f;
            m = x;
        } else {
            sum += expf(x - m);
        }
    }
    // wave reduce
    for (int off = 32; off; off >>= 1) {
        float m2 = __shfl_xor(m, off, 64);
        float s2 = __shfl_xor(sum, off, 64);
        float M = fmaxf(m, m2);
        sum = sum * expf(m - M) + s2 * expf(m2 - M);
        m = M;
    }
    __shared__ float sm_m[4], sm_s[4];
    if (lane == 0) { sm_m[w] = m; sm_s[w] = sum; }
    __syncthreads();
    if (tid == 0) {
        float M = sm_m[0], S = sm_s[0];
        for (int i = 1; i < 4; ++i) {
            float M2 = fmaxf(M, sm_m[i]);
            S = S * expf(M - M2) + sm_s[i] * expf(sm_m[i] - M2);
            M = M2;
        }
        part[(b * 8 + s) * 2 + 0] = M;
        part[(b * 8 + s) * 2 + 1] = S;
    }
}

// ---------------------------------------------------------------------------
// K5c: combine partials -> lse, normalize in place. grid 32*8 blocks.
// ---------------------------------------------------------------------------
__global__ __launch_bounds__(256) void k5c_norm(float* __restrict__ logits,
                                                const float* __restrict__ part) {
    int b = blockIdx.x >> 3, s = blockIdx.x & 7;
    int tid = threadIdx.x;
    float M = -INFINITY, S = 0.f;
#pragma unroll
    for (int i = 0; i < 8; ++i) {
        float mi = part[(b * 8 + i) * 2 + 0];
        float si = part[(b * 8 + i) * 2 + 1];
        float M2 = fmaxf(M, mi);
        S = S * expf(M - M2) + si * expf(mi - M2);
        M = M2;
    }
    float lse = M + logf(S);
    int start = s * SLICE;
    int end = min(start + SLICE, V);
    for (int v = start + tid; v < end; v += 256) {
        size_t idx = (size_t)b * V + v;
        logits[idx] = logits[idx] - lse;
    }
}

// ---------------------------------------------------------------------------
extern "C" void kernel_launch(void* const* d_in, const int* in_sizes, int n_in,
                              void* d_out, int out_size, void* d_ws, size_t ws_size,
                              hipStream_t stream) {
    const int* input_data = (const int*)d_in[0];
    const float* h0 = (const float*)d_in[1];
    const float* c0 = (const float*)d_in[2];
    const float* enc = (const float*)d_in[3];
    const float* emb = (const float*)d_in[4];
    const float* W_ih = (const float*)d_in[5];
    const float* W_hh = (const float*)d_in[6];
    const float* b_ih = (const float*)d_in[7];
    const float* b_hh = (const float*)d_in[8];
    const float* W_out = (const float*)d_in[9];
    const float* b_out = (const float*)d_in[10];

    float* out = (float*)d_out;
    float* logp = out;                    // [32][50257]
    float* h1 = out + 1608224;            // [32][512]
    float* c1 = out + 1624608;            // [32][512]
    float* attn = out + 1640992;          // [32][50]

    float* ws = (float*)d_ws;
    float* rnn_in = ws;                   // [32][1024]
    float* ctx = ws + 32768;              // [32][512]
    float* gates = ws + 49152;            // [32][2048]
    float* xout = ws + 114688;            // [32][1024]
    float* part = ws + 147456;            // [32][8][2]

    k1_attn<<<32, 256, 0, stream>>>(input_data, h0, enc, emb, attn, rnn_in, ctx);
    k2_gates<<<32, 256, 0, stream>>>(rnn_in, h0, W_ih, W_hh, b_ih, b_hh, gates);
    k3_lstm<<<64, 256, 0, stream>>>(gates, c0, ctx, h1, c1, xout);
    k4_logits<<<393, 256, 0, stream>>>(xout, W_out, b_out, logp);
    k5a_partial<<<256, 256, 0, stream>>>(logp, part);
    k5c_norm<<<256, 256, 0, stream>>>(logp, part);
}

// Round 3
// 797.199 us; speedup vs baseline: 1.3200x; 1.3200x over previous
//
#include <hip/hip_runtime.h>
#include <math.h>

#define H 512
#define V 50257
#define B 32
#define L 50

typedef float f4 __attribute__((ext_vector_type(4)));

__device__ __forceinline__ float sigmoidf_(float x) { return 1.f / (1.f + expf(-x)); }

__device__ __forceinline__ float dot4(f4 a, f4 b) {
    return a.x * b.x + a.y * b.y + a.z * b.z + a.w * b.w;
}

// ---------------------------------------------------------------------------
// K1: attention energies + softmax + context + embedding gather
// grid: 32 blocks (one per batch) x 256 threads
// ---------------------------------------------------------------------------
__global__ __launch_bounds__(256) void k1_attn(const int* __restrict__ input_data,
                                               const float* __restrict__ h0,
                                               const float* __restrict__ enc,
                                               const float* __restrict__ emb,
                                               float* __restrict__ attn_out,
                                               float* __restrict__ rnn_in,
                                               float* __restrict__ ctx) {
    int b = blockIdx.x;
    int tid = threadIdx.x;
    int lane = tid & 63, w = tid >> 6;
    __shared__ float sm[64];

    // energies[b][l] = <h0[b,:], enc[l,b,:]>
    for (int l = w; l < L; l += 4) {
        const f4* e4 = (const f4*)(enc + (size_t)(l * B + b) * H);
        const f4* h4 = (const f4*)(h0 + (size_t)b * H);
        float s = 0.f;
#pragma unroll
        for (int i = 0; i < 2; ++i) {
            s += dot4(e4[lane + 64 * i], h4[lane + 64 * i]);
        }
        for (int off = 32; off; off >>= 1) s += __shfl_down(s, off, 64);
        if (lane == 0) sm[l] = s;
    }
    __syncthreads();

    // softmax over l (wave 0)
    if (w == 0) {
        float e = (lane < L) ? sm[lane] : -INFINITY;
        float m = e;
        for (int off = 32; off; off >>= 1) m = fmaxf(m, __shfl_xor(m, off, 64));
        float p = (lane < L) ? expf(e - m) : 0.f;
        float s = p;
        for (int off = 32; off; off >>= 1) s += __shfl_xor(s, off, 64);
        float a = p / s;
        if (lane < L) {
            sm[lane] = a;
            attn_out[b * L + lane] = a;
        }
    }
    __syncthreads();

    // context[b][h] = sum_l attn[l] * enc[l,b,h]; rnn_in = [embedded | context]
    int idx = input_data[b];
    for (int h = tid; h < H; h += 256) {
        float c = 0.f;
#pragma unroll 5
        for (int l = 0; l < L; ++l) c += sm[l] * enc[(size_t)(l * B + b) * H + h];
        ctx[b * H + h] = c;
        rnn_in[b * 1024 + 512 + h] = c;
        rnn_in[b * 1024 + h] = emb[(size_t)idx * H + h];
    }
}

// ---------------------------------------------------------------------------
// K2: gates[b][n] = rnn_in[b,:] @ W_ih[n,:] + h0[b,:] @ W_hh[n,:] + b_ih + b_hh
// grid: 64 blocks x 256 threads; 32 rows/block; thread = 1 row x 4 batches;
// k-unroll 32 (8 f4 W loads in flight per iter). No NT hints.
// ---------------------------------------------------------------------------
__global__ __launch_bounds__(256) void k2_gates(const float* __restrict__ rnn_in,
                                                const float* __restrict__ h0,
                                                const float* __restrict__ W_ih,
                                                const float* __restrict__ W_hh,
                                                const float* __restrict__ b_ih,
                                                const float* __restrict__ b_hh,
                                                float* __restrict__ gates) {
    int t = threadIdx.x;
    int tn = t & 31, tb = t >> 5;
    int n = blockIdx.x * 32 + tn;   // gate row
    int b0 = tb * 4;                // 4 batches
    float acc[4] = {};

    const float* wih = W_ih + (size_t)n * 1024;
    for (int k = 0; k < 1024; k += 32) {
        f4 wv[8];
#pragma unroll
        for (int u = 0; u < 8; ++u) wv[u] = *(const f4*)(wih + k + u * 4);
#pragma unroll
        for (int u = 0; u < 8; ++u) {
#pragma unroll
            for (int i = 0; i < 4; ++i) {
                f4 xv = *(const f4*)(rnn_in + (b0 + i) * 1024 + k + u * 4);
                acc[i] += dot4(xv, wv[u]);
            }
        }
    }
    const float* whh = W_hh + (size_t)n * 512;
    for (int k = 0; k < 512; k += 32) {
        f4 wv[8];
#pragma unroll
        for (int u = 0; u < 8; ++u) wv[u] = *(const f4*)(whh + k + u * 4);
#pragma unroll
        for (int u = 0; u < 8; ++u) {
#pragma unroll
            for (int i = 0; i < 4; ++i) {
                f4 xv = *(const f4*)(h0 + (b0 + i) * 512 + k + u * 4);
                acc[i] += dot4(xv, wv[u]);
            }
        }
    }
    float bias = b_ih[n] + b_hh[n];
#pragma unroll
    for (int i = 0; i < 4; ++i)
        gates[(b0 + i) * 2048 + n] = acc[i] + bias;
}

// ---------------------------------------------------------------------------
// K3: LSTM pointwise; writes h1, c1 outputs and xout = [h1 | context]
// ---------------------------------------------------------------------------
__global__ __launch_bounds__(256) void k3_lstm(const float* __restrict__ gates,
                                               const float* __restrict__ c0,
                                               const float* __restrict__ ctx,
                                               float* __restrict__ h1_out,
                                               float* __restrict__ c1_out,
                                               float* __restrict__ xout) {
    int id = blockIdx.x * 256 + threadIdx.x;
    if (id >= B * H) return;
    int b = id >> 9, h = id & 511;
    const float* g = gates + b * 2048;
    float ig = g[h];
    float fg = g[512 + h];
    float gg = g[1024 + h];
    float og = g[1536 + h];
    float c = sigmoidf_(fg) * c0[id] + sigmoidf_(ig) * tanhf(gg);
    float hh = sigmoidf_(og) * tanhf(c);
    c1_out[id] = c;
    h1_out[id] = hh;
    xout[b * 1024 + h] = hh;
    xout[b * 1024 + 512 + h] = ctx[id];
}

// ---------------------------------------------------------------------------
// K4: logits[b][n] = xout[b,:] @ W_out[n,:] + b_out[n]
// grid: 786 blocks x 256 threads; 64 rows/block; thread = 2 rows x 4 batches;
// k-unroll 32 -> 16 independent contiguous W loads in flight per iter.
// No NT hints (L2 must complete the 64B lines across k-steps).
// ---------------------------------------------------------------------------
__global__ __launch_bounds__(256) void k4_logits(const float* __restrict__ xout,
                                                 const float* __restrict__ W_out,
                                                 const float* __restrict__ b_out,
                                                 float* __restrict__ logits) {
    int t = threadIdx.x;
    int tn = t & 31, tb = t >> 5;
    int n0 = blockIdx.x * 64 + tn * 2;
    int b0 = tb * 4;

    if (n0 + 1 < V) {
        const float* w0 = W_out + (size_t)n0 * 1024;
        const float* w1 = w0 + 1024;
        float acc0[4] = {}, acc1[4] = {};
        for (int k = 0; k < 1024; k += 32) {
            f4 wv0[8], wv1[8];
#pragma unroll
            for (int u = 0; u < 8; ++u) wv0[u] = *(const f4*)(w0 + k + u * 4);
#pragma unroll
            for (int u = 0; u < 8; ++u) wv1[u] = *(const f4*)(w1 + k + u * 4);
#pragma unroll
            for (int u = 0; u < 8; ++u) {
#pragma unroll
                for (int i = 0; i < 4; ++i) {
                    f4 xv = *(const f4*)(xout + (b0 + i) * 1024 + k + u * 4);
                    acc0[i] += dot4(xv, wv0[u]);
                    acc1[i] += dot4(xv, wv1[u]);
                }
            }
        }
        float bb0 = b_out[n0], bb1 = b_out[n0 + 1];
#pragma unroll
        for (int i = 0; i < 4; ++i) {
            logits[(size_t)(b0 + i) * V + n0] = acc0[i] + bb0;
            logits[(size_t)(b0 + i) * V + n0 + 1] = acc1[i] + bb1;
        }
    } else {
        // tail: per-row guarded (only the last block hits this)
        for (int j = 0; j < 2; ++j) {
            int n = n0 + j;
            if (n >= V) continue;
            const float* w = W_out + (size_t)n * 1024;
            float a[4] = {};
            for (int k = 0; k < 1024; k += 4) {
                f4 wv = *(const f4*)(w + k);
#pragma unroll
                for (int i = 0; i < 4; ++i) {
                    f4 xv = *(const f4*)(xout + (b0 + i) * 1024 + k);
                    a[i] += dot4(xv, wv);
                }
            }
#pragma unroll
            for (int i = 0; i < 4; ++i)
                logits[(size_t)(b0 + i) * V + n] = a[i] + b_out[n];
        }
    }
}

// ---------------------------------------------------------------------------
// K5a: per-(row, slice) online (max, sumexp) partials. grid 32*8 blocks.
// ---------------------------------------------------------------------------
#define SLICE 6283  // ceil(V/8)

__global__ __launch_bounds__(256) void k5a_partial(const float* __restrict__ logits,
                                                   float* __restrict__ part) {
    int b = blockIdx.x >> 3, s = blockIdx.x & 7;
    int tid = threadIdx.x;
    int lane = tid & 63, w = tid >> 6;
    int start = s * SLICE;
    int end = min(start + SLICE, V);

    float m = -INFINITY, sum = 0.f;
    for (int v = start + tid; v < end; v += 256) {
        float x = logits[(size_t)b * V + v];
        if (x > m) {
            sum = sum * expf(m - x) + 1.f;
            m = x;
        } else {
            sum += expf(x - m);
        }
    }
    // wave reduce
    for (int off = 32; off; off >>= 1) {
        float m2 = __shfl_xor(m, off, 64);
        float s2 = __shfl_xor(sum, off, 64);
        float M = fmaxf(m, m2);
        sum = sum * expf(m - M) + s2 * expf(m2 - M);
        m = M;
    }
    __shared__ float sm_m[4], sm_s[4];
    if (lane == 0) { sm_m[w] = m; sm_s[w] = sum; }
    __syncthreads();
    if (tid == 0) {
        float M = sm_m[0], S = sm_s[0];
        for (int i = 1; i < 4; ++i) {
            float M2 = fmaxf(M, sm_m[i]);
            S = S * expf(M - M2) + sm_s[i] * expf(sm_m[i] - M2);
            M = M2;
        }
        part[(b * 8 + s) * 2 + 0] = M;
        part[(b * 8 + s) * 2 + 1] = S;
    }
}

// ---------------------------------------------------------------------------
// K5c: combine partials -> lse, normalize in place. grid 32*8 blocks.
// ---------------------------------------------------------------------------
__global__ __launch_bounds__(256) void k5c_norm(float* __restrict__ logits,
                                                const float* __restrict__ part) {
    int b = blockIdx.x >> 3, s = blockIdx.x & 7;
    int tid = threadIdx.x;
    float M = -INFINITY, S = 0.f;
#pragma unroll
    for (int i = 0; i < 8; ++i) {
        float mi = part[(b * 8 + i) * 2 + 0];
        float si = part[(b * 8 + i) * 2 + 1];
        float M2 = fmaxf(M, mi);
        S = S * expf(M - M2) + si * expf(mi - M2);
        M = M2;
    }
    float lse = M + logf(S);
    int start = s * SLICE;
    int end = min(start + SLICE, V);
    for (int v = start + tid; v < end; v += 256) {
        size_t idx = (size_t)b * V + v;
        logits[idx] = logits[idx] - lse;
    }
}

// ---------------------------------------------------------------------------
extern "C" void kernel_launch(void* const* d_in, const int* in_sizes, int n_in,
                              void* d_out, int out_size, void* d_ws, size_t ws_size,
                              hipStream_t stream) {
    const int* input_data = (const int*)d_in[0];
    const float* h0 = (const float*)d_in[1];
    const float* c0 = (const float*)d_in[2];
    const float* enc = (const float*)d_in[3];
    const float* emb = (const float*)d_in[4];
    const float* W_ih = (const float*)d_in[5];
    const float* W_hh = (const float*)d_in[6];
    const float* b_ih = (const float*)d_in[7];
    const float* b_hh = (const float*)d_in[8];
    const float* W_out = (const float*)d_in[9];
    const float* b_out = (const float*)d_in[10];

    float* out = (float*)d_out;
    float* logp = out;                    // [32][50257]
    float* h1 = out + 1608224;            // [32][512]
    float* c1 = out + 1624608;            // [32][512]
    float* attn = out + 1640992;          // [32][50]

    float* ws = (float*)d_ws;
    float* rnn_in = ws;                   // [32][1024]
    float* ctx = ws + 32768;              // [32][512]
    float* gates = ws + 49152;            // [32][2048]
    float* xout = ws + 114688;            // [32][1024]
    float* part = ws + 147456;            // [32][8][2]

    k1_attn<<<32, 256, 0, stream>>>(input_data, h0, enc, emb, attn, rnn_in, ctx);
    k2_gates<<<64, 256, 0, stream>>>(rnn_in, h0, W_ih, W_hh, b_ih, b_hh, gates);
    k3_lstm<<<64, 256, 0, stream>>>(gates, c0, ctx, h1, c1, xout);
    k4_logits<<<786, 256, 0, stream>>>(xout, W_out, b_out, logp);
    k5a_partial<<<256, 256, 0, stream>>>(logp, part);
    k5c_norm<<<256, 256, 0, stream>>>(logp, part);
}